// Round 20
// baseline (746.999 us; speedup 1.0000x reference)
//
#include <hip/hip_runtime.h>
#include <hip/hip_bf16.h>
#include <math.h>

#define NHEAD 12
#define CDIM 384
#define QKVC 1152
#define MLPH 1536
#define SCALE 0.17677669529663687f  // 32^-0.5

typedef __attribute__((ext_vector_type(8))) short short8;
typedef __attribute__((ext_vector_type(4))) float f32x4;

static __device__ __forceinline__ unsigned short f2bf(float f) {
  union { __hip_bfloat16 b; unsigned short u; } c;
  c.b = __float2bfloat16(f);
  return c.u;
}

// tanh-form GELU in sigmoid representation: x*sigma(2y); 5 VALU + 1 trans. NaN-safe.
static __device__ __forceinline__ float gelu_f(float x) {
  float x2 = x * x;
  float t = __builtin_fmaf(0.044715f * x2, x, x);
  float e = __expf(-1.5957691216057308f * t);
  return x / (1.f + e);
}

// ------------- qkv of a padded (zero) token: ln1_b @ qkv_w + qkv_b -> bf16 -------------
__global__ void pad_qkv_kernel(const float* __restrict__ lb, const float* __restrict__ Wq,
                               const float* __restrict__ bq, __hip_bfloat16* __restrict__ outp) {
  int j = blockIdx.x * blockDim.x + threadIdx.x;
  if (j >= QKVC) return;
  float s = bq[j];
  for (int c = 0; c < CDIM; c++) s += lb[c] * Wq[(size_t)c * QKVC + j];
  outp[j] = __float2bfloat16(s);
}

// ------------- expand relative-position bias to padded [12][64][64] f32 -------------
__global__ void expand_bias(const float* __restrict__ biases, const int* __restrict__ bidx,
                            float* __restrict__ Bexp, int n_off) {
  int h = blockIdx.x;
  for (int e = threadIdx.x; e < 4096; e += 256) {
    int n = e >> 6, m = e & 63;
    float v;
    if (m >= 49) v = -1e30f;
    else if (n >= 49) v = 0.f;
    else v = biases[h * n_off + bidx[n * 49 + m]];
    Bexp[h * 4096 + e] = v;
  }
}

// -------- pack qkv_w [384][1152] into MFMA fragment order: f = G*12 + kk --------
__global__ void wfragq(const float* __restrict__ W, unsigned short* __restrict__ WF) {
  int f = blockIdx.x;
  int lane = threadIdx.x;
  int kk = f % 12, G = f / 12;
  int n = G * 16 + (lane & 15);
  int k = kk * 32 + (lane >> 4) * 8;
  unsigned short* dst = WF + ((size_t)f * 64 + lane) * 8;
#pragma unroll
  for (int j = 0; j < 8; j++) dst[j] = f2bf(W[(size_t)(k + j) * QKVC + n]);
}

// -------- pack proj_w [384][384] into MFMA fragment order: f = G*12 + kk (G=0..23) --------
__global__ void wfragp(const float* __restrict__ W, unsigned short* __restrict__ WF) {
  int f = blockIdx.x;
  int lane = threadIdx.x;
  int kk = f % 12, G = f / 12;
  int n = G * 16 + (lane & 15);
  int k = kk * 32 + (lane >> 4) * 8;
  unsigned short* dst = WF + ((size_t)f * 64 + lane) * 8;
#pragma unroll
  for (int j = 0; j < 8; j++) dst[j] = f2bf(W[(size_t)(k + j) * CDIM + n]);
}

// -------- pack fc1_w [384][1536] into phase-1 MFMA fragment order (1m x 8n waves) --------
__global__ void wfrag1(const float* __restrict__ W, unsigned short* __restrict__ WF) {
  int f = blockIdx.x;
  int lane = threadIdx.x;
  int wn = f & 7, kk = (f >> 3) % 12, ks = f / 96;
  int n = ks * 128 + wn * 16 + (lane & 15);
  int k = kk * 32 + (lane >> 4) * 8;
  unsigned short* dst = WF + ((size_t)f * 64 + lane) * 8;
#pragma unroll
  for (int j = 0; j < 8; j++) dst[j] = f2bf(W[(size_t)(k + j) * MLPH + n]);
}

// -------- pack fc2_w [1536][384] into phase-2 MFMA fragment order (1m x 8n waves) --------
__global__ void wfrag2(const float* __restrict__ W, unsigned short* __restrict__ WF) {
  int f = blockIdx.x;
  int lane = threadIdx.x;
  int j = f % 3, wn = (f / 3) & 7, kk = (f / 24) & 3, ks = f / 96;
  int n = wn * 48 + j * 16 + (lane & 15);
  int k = ks * 128 + kk * 32 + (lane >> 4) * 8;
  unsigned short* dst = WF + ((size_t)f * 64 + lane) * 8;
#pragma unroll
  for (int jj = 0; jj < 8; jj++) dst[jj] = f2bf(W[(size_t)(k + jj) * CDIM + n]);
}

// ---------------- fused LN1 + QKV GEMM ----------------
__global__ __launch_bounds__(512) void ln_qkv(
    const float* __restrict__ X, const float* __restrict__ g, const float* __restrict__ b,
    const unsigned short* __restrict__ WQF, const float* __restrict__ BQ,
    __hip_bfloat16* __restrict__ QKV) {
  __shared__ unsigned short Al[64][388];
  int tid = threadIdx.x;
  int m0 = blockIdx.x * 64;
  int wave = tid >> 6, lane = tid & 63;
  int l15 = lane & 15, l4 = lane >> 4;

#pragma unroll
  for (int r8 = 0; r8 < 8; r8++) {
    int row = wave * 8 + r8;
    const float* xr = X + (size_t)(m0 + row) * CDIM;
    float vals[6];
    float s = 0.f;
#pragma unroll
    for (int i = 0; i < 6; i++) { vals[i] = xr[lane + i * 64]; s += vals[i]; }
#pragma unroll
    for (int o = 32; o > 0; o >>= 1) s += __shfl_xor(s, o);
    float mean = s * (1.f / 384.f);
    float vs = 0.f;
#pragma unroll
    for (int i = 0; i < 6; i++) { float d = vals[i] - mean; vs += d * d; }
#pragma unroll
    for (int o = 32; o > 0; o >>= 1) vs += __shfl_xor(vs, o);
    float rs = rsqrtf(vs * (1.f / 384.f) + 1e-5f);
#pragma unroll
    for (int i = 0; i < 6; i++) {
      int c = lane + i * 64;
      Al[row][c] = f2bf((vals[i] - mean) * rs * g[c] + b[c]);
    }
  }
  __syncthreads();

  for (int rd = 0; rd < 9; rd++) {
    int G = rd * 8 + wave;
    f32x4 acc[4] = {};
    const unsigned short* wb = WQF + (size_t)(G * 12) * 512 + lane * 8;
#pragma unroll
    for (int kk = 0; kk < 12; kk++) {
      short8 bf = *(const short8*)(wb + kk * 512);
#pragma unroll
      for (int i = 0; i < 4; i++) {
        short8 af = *(const short8*)&Al[i * 16 + l15][kk * 32 + l4 * 8];
        acc[i] = __builtin_amdgcn_mfma_f32_16x16x32_bf16(af, bf, acc[i], 0, 0, 0);
      }
    }
    int n = G * 16 + l15;
    float bv = BQ[n];
    __hip_bfloat16* dst = QKV + (size_t)m0 * QKVC + n;
#pragma unroll
    for (int i = 0; i < 4; i++)
#pragma unroll
      for (int r = 0; r < 4; r++)
        dst[(size_t)(i * 16 + l4 * 4 + r) * QKVC] = __float2bfloat16(acc[i][r] + bv);
  }
}

// ---------------- proj + residual: staged-A, one barrier, fragment-packed weights ----------------
__global__ __launch_bounds__(512) void proj_res(
    const __hip_bfloat16* __restrict__ AW, const unsigned short* __restrict__ WPF,
    const float* __restrict__ BP, const float* __restrict__ X,
    __hip_bfloat16* __restrict__ X1) {
  __shared__ unsigned short Al[64][388];
  int tid = threadIdx.x;
  int m0 = blockIdx.x * 64;
  int wave = tid >> 6, lane = tid & 63;
  int l15 = lane & 15, l4 = lane >> 4;

  {
#pragma unroll
    for (int i = 0; i < 6; i++) {
      int u = tid + i * 512;
      int r = u / 48, col = (u % 48) * 8;
      *(uint4*)&Al[r][col] =
          *(const uint4*)((const unsigned short*)AW + (size_t)(m0 + r) * 384 + col);
    }
  }
  __syncthreads();

  f32x4 acc[4][3] = {};
#pragma unroll
  for (int kk = 0; kk < 12; kk++) {
    short8 af[4];
#pragma unroll
    for (int i = 0; i < 4; i++)
      af[i] = *(const short8*)&Al[i * 16 + l15][kk * 32 + l4 * 8];
#pragma unroll
    for (int j = 0; j < 3; j++) {
      int G = wave * 3 + j;
      short8 bf = *(const short8*)(WPF + (size_t)(G * 12 + kk) * 512 + lane * 8);
#pragma unroll
      for (int i = 0; i < 4; i++)
        acc[i][j] = __builtin_amdgcn_mfma_f32_16x16x32_bf16(af[i], bf, acc[i][j], 0, 0, 0);
    }
  }
#pragma unroll
  for (int j = 0; j < 3; j++) {
    int n = (wave * 3 + j) * 16 + l15;
    float bv = BP[n];
#pragma unroll
    for (int i = 0; i < 4; i++)
#pragma unroll
      for (int r = 0; r < 4; r++) {
        int m = m0 + i * 16 + l4 * 4 + r;
        X1[(size_t)m * 384 + n] =
            __float2bfloat16(acc[i][j][r] + bv + X[(size_t)m * 384 + n]);
      }
  }
}

// -------- fused MLP (R16 dataflow) + W1 AND W2 register ping-pong prefetch --------
// 8 waves 1m x 8n, BM=64, 24 barriers; next ks's 12 W1 + 12 W2 frags prefetched
// into registers at iteration top so all L2 latency hides under compute.
__global__ __launch_bounds__(512, 2) void mlp_fused(
    const __hip_bfloat16* __restrict__ XN, const unsigned short* __restrict__ W1F,
    const float* __restrict__ B1, const unsigned short* __restrict__ W2F,
    const float* __restrict__ B2, const __hip_bfloat16* __restrict__ X2,
    float* __restrict__ OUT) {
  __shared__ unsigned short XNl[64][388];
  __shared__ unsigned short Hl[64][132];
  int tid = threadIdx.x;
  int m0 = blockIdx.x * 64;
  int wave = tid >> 6, lane = tid & 63;
  int wn = wave;
  int l15 = lane & 15, l4 = lane >> 4;

  {
#pragma unroll
    for (int i = 0; i < 6; i++) {
      int u = tid + i * 512;
      int r = u / 48, col = (u % 48) * 8;
      *(uint4*)&XNl[r][col] =
          *(const uint4*)((const unsigned short*)XN + (size_t)(m0 + r) * 384 + col);
    }
  }

  f32x4 acc[4][3] = {};
  // W1 frag f = ks*96 + kk*8 + wn  (shorts: f*512); W2 frag f = ks*96 + kk*24 + wn*3 + j.
  const unsigned short* w1b0 = W1F + (size_t)wn * 512 + lane * 8;
  const unsigned short* w2b0 = W2F + (size_t)(wn * 3) * 512 + lane * 8;
  short8 wA[12], wB[12], vA[12], vB[12];
#pragma unroll
  for (int kk = 0; kk < 12; kk++)
    wA[kk] = *(const short8*)(w1b0 + kk * 4096);
#pragma unroll
  for (int kk = 0; kk < 4; kk++)
#pragma unroll
    for (int j = 0; j < 3; j++)
      vA[kk * 3 + j] = *(const short8*)(w2b0 + kk * 12288 + j * 512);

  __syncthreads();

  for (int S = 0; S < 6; S++) {
    // ================= ks = 2S : consume wA/vA, prefetch wB/vB(ks+1) =================
    {
      const int ks = 2 * S;
#pragma unroll
      for (int kk = 0; kk < 12; kk++)
        wB[kk] = *(const short8*)(w1b0 + (size_t)(ks + 1) * 49152 + kk * 4096);
#pragma unroll
      for (int kk = 0; kk < 4; kk++)
#pragma unroll
        for (int j = 0; j < 3; j++)
          vB[kk * 3 + j] =
              *(const short8*)(w2b0 + (size_t)(ks + 1) * 49152 + kk * 12288 + j * 512);
      f32x4 hacc[4] = {};
#pragma unroll
      for (int kk = 0; kk < 12; kk++)
#pragma unroll
        for (int i = 0; i < 4; i++) {
          short8 af = *(const short8*)&XNl[i * 16 + l15][kk * 32 + l4 * 8];
          hacc[i] = __builtin_amdgcn_mfma_f32_16x16x32_bf16(af, wA[kk], hacc[i], 0, 0, 0);
        }
      float b1v = B1[ks * 128 + wn * 16 + l15];
      __syncthreads();
#pragma unroll
      for (int i = 0; i < 4; i++)
#pragma unroll
        for (int r = 0; r < 4; r++) {
          float c = hacc[i][r] + b1v;
          Hl[i * 16 + l4 * 4 + r][wn * 16 + l15] = f2bf(gelu_f(c));
        }
      __syncthreads();
#pragma unroll
      for (int kk = 0; kk < 4; kk++) {
        short8 af2[4];
#pragma unroll
        for (int i = 0; i < 4; i++)
          af2[i] = *(const short8*)&Hl[i * 16 + l15][kk * 32 + l4 * 8];
#pragma unroll
        for (int j = 0; j < 3; j++)
#pragma unroll
          for (int i = 0; i < 4; i++)
            acc[i][j] =
                __builtin_amdgcn_mfma_f32_16x16x32_bf16(af2[i], vA[kk * 3 + j], acc[i][j], 0, 0, 0);
      }
    }
    // ================= ks = 2S+1 : consume wB/vB, prefetch wA/vA(next) =================
    {
      const int ks = 2 * S + 1;
      const int ksn = (ks + 1 < 12) ? (ks + 1) : 0;
#pragma unroll
      for (int kk = 0; kk < 12; kk++)
        wA[kk] = *(const short8*)(w1b0 + (size_t)ksn * 49152 + kk * 4096);
#pragma unroll
      for (int kk = 0; kk < 4; kk++)
#pragma unroll
        for (int j = 0; j < 3; j++)
          vA[kk * 3 + j] =
              *(const short8*)(w2b0 + (size_t)ksn * 49152 + kk * 12288 + j * 512);
      f32x4 hacc[4] = {};
#pragma unroll
      for (int kk = 0; kk < 12; kk++)
#pragma unroll
        for (int i = 0; i < 4; i++) {
          short8 af = *(const short8*)&XNl[i * 16 + l15][kk * 32 + l4 * 8];
          hacc[i] = __builtin_amdgcn_mfma_f32_16x16x32_bf16(af, wB[kk], hacc[i], 0, 0, 0);
        }
      float b1v = B1[ks * 128 + wn * 16 + l15];
      __syncthreads();
#pragma unroll
      for (int i = 0; i < 4; i++)
#pragma unroll
        for (int r = 0; r < 4; r++) {
          float c = hacc[i][r] + b1v;
          Hl[i * 16 + l4 * 4 + r][wn * 16 + l15] = f2bf(gelu_f(c));
        }
      __syncthreads();
#pragma unroll
      for (int kk = 0; kk < 4; kk++) {
        short8 af2[4];
#pragma unroll
        for (int i = 0; i < 4; i++)
          af2[i] = *(const short8*)&Hl[i * 16 + l15][kk * 32 + l4 * 8];
#pragma unroll
        for (int j = 0; j < 3; j++)
#pragma unroll
          for (int i = 0; i < 4; i++)
            acc[i][j] =
                __builtin_amdgcn_mfma_f32_16x16x32_bf16(af2[i], vB[kk * 3 + j], acc[i][j], 0, 0, 0);
      }
    }
  }
#pragma unroll
  for (int j = 0; j < 3; j++) {
    int n = wn * 48 + j * 16 + l15;
    float bv = B2[n];
#pragma unroll
    for (int i = 0; i < 4; i++)
#pragma unroll
      for (int r = 0; r < 4; r++) {
        int m = m0 + i * 16 + l4 * 4 + r;
        OUT[(size_t)m * 384 + n] =
            acc[i][j][r] + bv + __bfloat162float(X2[(size_t)m * 384 + n]);
      }
  }
}

// ---------------- MFMA window attention: 1 wave per (window, head) ----------------
__global__ __launch_bounds__(64) void attn_mfma(
    const __hip_bfloat16* __restrict__ qkv, const __hip_bfloat16* __restrict__ qkv_pad,
    const float* __restrict__ Bexp, __hip_bfloat16* __restrict__ aw) {
  int h = blockIdx.x % NHEAD;
  int w = blockIdx.x / NHEAD;
  int b = w / 25, wi = w % 25;
  int wh = wi / 5, wv = wi % 5;

  __shared__ unsigned short Q[64][40];
  __shared__ unsigned short K[64][40];
  __shared__ unsigned short Vt[32][72];
  __shared__ unsigned short P[64][72];

  int lane = threadIdx.x;
  int l15 = lane & 15, l4 = lane >> 4;

  {
    int t = lane;
    uint4 z = {0, 0, 0, 0};
    uint4 qv[4], kv[4];
    union { uint4 u[4]; unsigned short s[32]; } vu;
    bool use = t < 49;
    const unsigned short* src = (const unsigned short*)qkv_pad + h * 96;
    if (use) {
      int hh = wh * 7 + t / 7, ww = wv * 7 + t % 7;
      if (hh < 32 && ww < 32)
        src = (const unsigned short*)qkv + (size_t)(b * 1024 + hh * 32 + ww) * QKVC + h * 96;
    }
#pragma unroll
    for (int c = 0; c < 4; c++) {
      qv[c]   = use ? *(const uint4*)(src + c * 8)      : z;
      kv[c]   = use ? *(const uint4*)(src + 32 + c * 8) : z;
      vu.u[c] = use ? *(const uint4*)(src + 64 + c * 8) : z;
    }
#pragma unroll
    for (int c = 0; c < 4; c++) {
      *(uint4*)&Q[t][c * 8] = qv[c];
      *(uint4*)&K[t][c * 8] = kv[c];
    }
#pragma unroll
    for (int d = 0; d < 32; d++) Vt[d][t] = vu.s[d];
  }
  __syncthreads();

  f32x4 acc[4][4] = {};
  {
    short8 aq[4], bk[4];
#pragma unroll
    for (int i = 0; i < 4; i++) aq[i] = *(const short8*)&Q[i * 16 + l15][l4 * 8];
#pragma unroll
    for (int j = 0; j < 4; j++) bk[j] = *(const short8*)&K[j * 16 + l15][l4 * 8];
#pragma unroll
    for (int i = 0; i < 4; i++)
#pragma unroll
      for (int j = 0; j < 4; j++)
        acc[i][j] = __builtin_amdgcn_mfma_f32_16x16x32_bf16(aq[i], bk[j], acc[i][j], 0, 0, 0);
  }

  const float* Bh = Bexp + h * 4096;
  float rinv_[4][4];
#pragma unroll
  for (int i = 0; i < 4; i++) {
    float s[4][4];
#pragma unroll
    for (int j = 0; j < 4; j++)
#pragma unroll
      for (int r = 0; r < 4; r++) {
        int n = i * 16 + l4 * 4 + r, m = j * 16 + l15;
        s[j][r] = acc[i][j][r] * SCALE + Bh[n * 64 + m];
      }
#pragma unroll
    for (int r = 0; r < 4; r++) {
      float mx = fmaxf(fmaxf(s[0][r], s[1][r]), fmaxf(s[2][r], s[3][r]));
#pragma unroll
      for (int o = 1; o < 16; o <<= 1) mx = fmaxf(mx, __shfl_xor(mx, o));
      float p[4], sm = 0.f;
#pragma unroll
      for (int j = 0; j < 4; j++) { p[j] = __expf(s[j][r] - mx); sm += p[j]; }
#pragma unroll
      for (int o = 1; o < 16; o <<= 1) sm += __shfl_xor(sm, o);
      rinv_[i][r] = 1.f / sm;
      int n = i * 16 + l4 * 4 + r;
#pragma unroll
      for (int j = 0; j < 4; j++) P[n][j * 16 + l15] = f2bf(p[j]);
    }
  }
  __syncthreads();

  f32x4 o[4][2] = {};
#pragma unroll
  for (int ks = 0; ks < 2; ks++) {
    short8 pa[4], vb[2];
#pragma unroll
    for (int i = 0; i < 4; i++) pa[i] = *(const short8*)&P[i * 16 + l15][ks * 32 + l4 * 8];
#pragma unroll
    for (int j = 0; j < 2; j++) vb[j] = *(const short8*)&Vt[j * 16 + l15][ks * 32 + l4 * 8];
#pragma unroll
    for (int i = 0; i < 4; i++)
#pragma unroll
      for (int j = 0; j < 2; j++)
        o[i][j] = __builtin_amdgcn_mfma_f32_16x16x32_bf16(pa[i], vb[j], o[i][j], 0, 0, 0);
  }

#pragma unroll
  for (int i = 0; i < 4; i++)
#pragma unroll
    for (int r = 0; r < 4; r++) {
      int n = i * 16 + l4 * 4 + r;
      if (n < 49) {
        int hh = wh * 7 + n / 7, ww = wv * 7 + n % 7;
        if (hh < 32 && ww < 32) {
          __hip_bfloat16* dst = aw + (size_t)(b * 1024 + hh * 32 + ww) * CDIM + h * 32;
          float ri = rinv_[i][r];
#pragma unroll
          for (int j = 0; j < 2; j++)
            dst[j * 16 + l15] = __float2bfloat16(o[i][j][r] * ri);
        }
      }
    }
}

// ------- fused depthwise 3x3 conv + BN + LN2 (x1 bf16 in, x2 bf16 out) -------
__global__ __launch_bounds__(384) void conv_bn_ln_kernel(
    const __hip_bfloat16* __restrict__ X, const float* __restrict__ W9,
    const float* __restrict__ g, const float* __restrict__ bb,
    const float* __restrict__ mm, const float* __restrict__ vv,
    const float* __restrict__ lg, const float* __restrict__ lb,
    __hip_bfloat16* __restrict__ X2, __hip_bfloat16* __restrict__ XN) {
  int nwg = gridDim.x;
  int id = blockIdx.x;
  int nid = (id & 7) * (nwg >> 3) + (id >> 3);
  int yh = nid & 1;
  int x = (nid >> 1) & 31;
  int b = nid >> 6;
  int c = threadIdx.x;

  float w[9];
#pragma unroll
  for (int i = 0; i < 9; i++) w[i] = W9[c * 9 + i];
  float bnsc = rsqrtf(vv[c] + 1e-5f) * g[c];
  float bnsh = bb[c] - mm[c] * bnsc;
  float lgc = lg[c], lbc = lb[c];

  bool xm = x > 0, xp = x < 31;
  const __hip_bfloat16* colbase = X + ((size_t)(b * 1024 + x)) * CDIM + c;

  __shared__ float part[2][6][2];
  int wv = threadIdx.x >> 6, ln = threadIdx.x & 63;

  float w0[3], w1[3], w2[3];
  int y0 = yh * 16;
  if (y0 == 0) {
    w0[0] = w0[1] = w0[2] = 0.f;
  } else {
    const __hip_bfloat16* p = colbase + (size_t)(y0 - 1) * 32 * CDIM;
    w0[0] = xm ? __bfloat162float(p[-CDIM]) : 0.f;
    w0[1] = __bfloat162float(p[0]);
    w0[2] = xp ? __bfloat162float(p[CDIM]) : 0.f;
  }
  {
    const __hip_bfloat16* p = colbase + (size_t)y0 * 32 * CDIM;
    w1[0] = xm ? __bfloat162float(p[-CDIM]) : 0.f;
    w1[1] = __bfloat162float(p[0]);
    w1[2] = xp ? __bfloat162float(p[CDIM]) : 0.f;
  }

  for (int y = y0; y < y0 + 16; y++) {
    if (y + 1 < 32) {
      const __hip_bfloat16* p = colbase + (size_t)(y + 1) * 32 * CDIM;
      w2[0] = xm ? __bfloat162float(p[-CDIM]) : 0.f;
      w2[1] = __bfloat162float(p[0]);
      w2[2] = xp ? __bfloat162float(p[CDIM]) : 0.f;
    } else {
      w2[0] = w2[1] = w2[2] = 0.f;
    }
    float acc = w0[0] * w[0] + w0[1] * w[1] + w0[2] * w[2]
              + w1[0] * w[3] + w1[1] * w[4] + w1[2] * w[5]
              + w2[0] * w[6] + w2[1] * w[7] + w2[2] * w[8];
    float r = acc * bnsc + bnsh;
    size_t tok = (size_t)(b * 1024 + y * 32 + x);
    X2[tok * CDIM + c] = __float2bfloat16(r);

    float s1 = r, s2 = r * r;
#pragma unroll
    for (int o = 32; o > 0; o >>= 1) { s1 += __shfl_xor(s1, o); s2 += __shfl_xor(s2, o); }
    int pb = y & 1;
    if (ln == 0) { part[pb][wv][0] = s1; part[pb][wv][1] = s2; }
    __syncthreads();
    float ts1 = 0.f, ts2 = 0.f;
#pragma unroll
    for (int i = 0; i < 6; i++) { ts1 += part[pb][i][0]; ts2 += part[pb][i][1]; }
    float mean = ts1 * (1.f / 384.f);
    float var = ts2 * (1.f / 384.f) - mean * mean;
    float rstd = rsqrtf(var + 1e-5f);
    XN[tok * CDIM + c] = __float2bfloat16((r - mean) * rstd * lgc + lbc);

    w0[0] = w1[0]; w0[1] = w1[1]; w0[2] = w1[2];
    w1[0] = w2[0]; w1[1] = w2[1]; w1[2] = w2[2];
  }
}

extern "C" void kernel_launch(void* const* d_in, const int* in_sizes, int n_in,
                              void* d_out, int out_size, void* d_ws, size_t ws_size,
                              hipStream_t stream) {
  const float* x      = (const float*)d_in[0];
  const float* ln1_g  = (const float*)d_in[1];
  const float* ln1_b  = (const float*)d_in[2];
  const float* qkv_w  = (const float*)d_in[3];
  const float* qkv_b  = (const float*)d_in[4];
  const float* proj_w = (const float*)d_in[5];
  const float* proj_b = (const float*)d_in[6];
  const float* att_b  = (const float*)d_in[7];
  const float* conv_w = (const float*)d_in[8];
  const float* bn_g   = (const float*)d_in[9];
  const float* bn_b   = (const float*)d_in[10];
  const float* bn_m   = (const float*)d_in[11];
  const float* bn_v   = (const float*)d_in[12];
  const float* ln2_g  = (const float*)d_in[13];
  const float* ln2_b  = (const float*)d_in[14];
  const float* fc1_w  = (const float*)d_in[15];
  const float* fc1_b  = (const float*)d_in[16];
  const float* fc2_w  = (const float*)d_in[17];
  const float* fc2_b  = (const float*)d_in[18];
  const int* bias_idxs = (const int*)d_in[19];
  int n_off = in_sizes[7] / NHEAD;
  float* out = (float*)d_out;

  char* ws = (char*)d_ws;
  size_t off = 0;
  __hip_bfloat16* qkv_pad = (__hip_bfloat16*)(ws + off); off += QKVC * 2;
  off = (off + 255) & ~(size_t)255;
  float* Bexp = (float*)(ws + off); off += (size_t)NHEAD * 4096 * 4;
  unsigned short* wqf = (unsigned short*)(ws + off); off += (size_t)QKVC * CDIM * 2;
  unsigned short* wpf = (unsigned short*)(ws + off); off += (size_t)CDIM * CDIM * 2;
  unsigned short* w1f = (unsigned short*)(ws + off); off += (size_t)MLPH * CDIM * 2;
  unsigned short* w2f = (unsigned short*)(ws + off); off += (size_t)CDIM * MLPH * 2;
  size_t HDR = (off + 255) & ~(size_t)255;

  const size_t PER_TOK = 4608;
  int Bc = 64;
  while (Bc > 1 && HDR + (size_t)Bc * 1024 * PER_TOK > ws_size) Bc >>= 1;
  size_t Tc = (size_t)Bc * 1024;

  off = HDR;
  __hip_bfloat16* xn = (__hip_bfloat16*)(ws + off); off += Tc * CDIM * 2;
  __hip_bfloat16* qkv = (__hip_bfloat16*)(ws + off); off += Tc * QKVC * 2;
  __hip_bfloat16* x1 = qkv;  // alias: qkv dead after attn_mfma
  __hip_bfloat16* awb = (__hip_bfloat16*)(ws + off); off += Tc * CDIM * 2;
  __hip_bfloat16* x2 = (__hip_bfloat16*)(ws + off); off += Tc * CDIM * 2;

  pad_qkv_kernel<<<dim3(5), dim3(256), 0, stream>>>(ln1_b, qkv_w, qkv_b, qkv_pad);
  expand_bias<<<dim3(NHEAD), dim3(256), 0, stream>>>(att_b, bias_idxs, Bexp, n_off);
  wfragq<<<dim3(864), dim3(64), 0, stream>>>(qkv_w, wqf);
  wfragp<<<dim3(288), dim3(64), 0, stream>>>(proj_w, wpf);
  wfrag1<<<dim3(1152), dim3(64), 0, stream>>>(fc1_w, w1f);
  wfrag2<<<dim3(1152), dim3(64), 0, stream>>>(fc2_w, w2f);

  for (int b0 = 0; b0 < 64; b0 += Bc) {
    const float* xa = x + (size_t)b0 * 1024 * CDIM;
    float* outa = out + (size_t)b0 * 1024 * CDIM;
    int M = (int)Tc;

    ln_qkv<<<dim3(M / 64), dim3(512), 0, stream>>>(xa, ln1_g, ln1_b, wqf, qkv_b, qkv);
    attn_mfma<<<dim3(Bc * 25 * NHEAD), dim3(64), 0, stream>>>(qkv, qkv_pad, Bexp, awb);
    proj_res<<<dim3(M / 64), dim3(512), 0, stream>>>(awb, wpf, proj_b, xa, x1);
    conv_bn_ln_kernel<<<dim3(Bc * 64), dim3(384), 0, stream>>>(
        x1, conv_w, bn_g, bn_b, bn_m, bn_v, ln2_g, ln2_b, x2, xn);
    mlp_fused<<<dim3(M / 64), dim3(512), 0, stream>>>(
        xn, w1f, fc1_b, w2f, fc2_b, x2, outa);
  }
}

// Round 21
// 729.928 us; speedup vs baseline: 1.0234x; 1.0234x over previous
//
#include <hip/hip_runtime.h>
#include <hip/hip_bf16.h>
#include <math.h>

#define NHEAD 12
#define CDIM 384
#define QKVC 1152
#define MLPH 1536
#define SCALE 0.17677669529663687f  // 32^-0.5

typedef __attribute__((ext_vector_type(8))) short short8;
typedef __attribute__((ext_vector_type(4))) float f32x4;

static __device__ __forceinline__ unsigned short f2bf(float f) {
  union { __hip_bfloat16 b; unsigned short u; } c;
  c.b = __float2bfloat16(f);
  return c.u;
}

// tanh-form GELU in sigmoid representation: x*sigma(2y); 5 VALU + 1 trans. NaN-safe.
static __device__ __forceinline__ float gelu_f(float x) {
  float x2 = x * x;
  float t = __builtin_fmaf(0.044715f * x2, x, x);
  float e = __expf(-1.5957691216057308f * t);
  return x / (1.f + e);
}

// ------------- qkv of a padded (zero) token: ln1_b @ qkv_w + qkv_b -> bf16 -------------
__global__ void pad_qkv_kernel(const float* __restrict__ lb, const float* __restrict__ Wq,
                               const float* __restrict__ bq, __hip_bfloat16* __restrict__ outp) {
  int j = blockIdx.x * blockDim.x + threadIdx.x;
  if (j >= QKVC) return;
  float s = bq[j];
  for (int c = 0; c < CDIM; c++) s += lb[c] * Wq[(size_t)c * QKVC + j];
  outp[j] = __float2bfloat16(s);
}

// ------------- expand relative-position bias to padded [12][64][64] f32 -------------
__global__ void expand_bias(const float* __restrict__ biases, const int* __restrict__ bidx,
                            float* __restrict__ Bexp, int n_off) {
  int h = blockIdx.x;
  for (int e = threadIdx.x; e < 4096; e += 256) {
    int n = e >> 6, m = e & 63;
    float v;
    if (m >= 49) v = -1e30f;
    else if (n >= 49) v = 0.f;
    else v = biases[h * n_off + bidx[n * 49 + m]];
    Bexp[h * 4096 + e] = v;
  }
}

// -------- pack qkv_w [384][1152] into MFMA fragment order: f = G*12 + kk --------
__global__ void wfragq(const float* __restrict__ W, unsigned short* __restrict__ WF) {
  int f = blockIdx.x;
  int lane = threadIdx.x;
  int kk = f % 12, G = f / 12;
  int n = G * 16 + (lane & 15);
  int k = kk * 32 + (lane >> 4) * 8;
  unsigned short* dst = WF + ((size_t)f * 64 + lane) * 8;
#pragma unroll
  for (int j = 0; j < 8; j++) dst[j] = f2bf(W[(size_t)(k + j) * QKVC + n]);
}

// -------- pack proj_w [384][384] into MFMA fragment order: f = G*12 + kk (G=0..23) --------
__global__ void wfragp(const float* __restrict__ W, unsigned short* __restrict__ WF) {
  int f = blockIdx.x;
  int lane = threadIdx.x;
  int kk = f % 12, G = f / 12;
  int n = G * 16 + (lane & 15);
  int k = kk * 32 + (lane >> 4) * 8;
  unsigned short* dst = WF + ((size_t)f * 64 + lane) * 8;
#pragma unroll
  for (int j = 0; j < 8; j++) dst[j] = f2bf(W[(size_t)(k + j) * CDIM + n]);
}

// -------- pack fc1_w [384][1536] into phase-1 MFMA fragment order (1m x 8n waves) --------
__global__ void wfrag1(const float* __restrict__ W, unsigned short* __restrict__ WF) {
  int f = blockIdx.x;
  int lane = threadIdx.x;
  int wn = f & 7, kk = (f >> 3) % 12, ks = f / 96;
  int n = ks * 128 + wn * 16 + (lane & 15);
  int k = kk * 32 + (lane >> 4) * 8;
  unsigned short* dst = WF + ((size_t)f * 64 + lane) * 8;
#pragma unroll
  for (int j = 0; j < 8; j++) dst[j] = f2bf(W[(size_t)(k + j) * MLPH + n]);
}

// -------- pack fc2_w [1536][384] into phase-2 MFMA fragment order (1m x 8n waves) --------
__global__ void wfrag2(const float* __restrict__ W, unsigned short* __restrict__ WF) {
  int f = blockIdx.x;
  int lane = threadIdx.x;
  int j = f % 3, wn = (f / 3) & 7, kk = (f / 24) & 3, ks = f / 96;
  int n = wn * 48 + j * 16 + (lane & 15);
  int k = ks * 128 + kk * 32 + (lane >> 4) * 8;
  unsigned short* dst = WF + ((size_t)f * 64 + lane) * 8;
#pragma unroll
  for (int jj = 0; jj < 8; jj++) dst[jj] = f2bf(W[(size_t)(k + jj) * CDIM + n]);
}

// ---------------- fused LN1 + QKV GEMM ----------------
__global__ __launch_bounds__(512) void ln_qkv(
    const float* __restrict__ X, const float* __restrict__ g, const float* __restrict__ b,
    const unsigned short* __restrict__ WQF, const float* __restrict__ BQ,
    __hip_bfloat16* __restrict__ QKV) {
  __shared__ unsigned short Al[64][388];
  int tid = threadIdx.x;
  int m0 = blockIdx.x * 64;
  int wave = tid >> 6, lane = tid & 63;
  int l15 = lane & 15, l4 = lane >> 4;

#pragma unroll
  for (int r8 = 0; r8 < 8; r8++) {
    int row = wave * 8 + r8;
    const float* xr = X + (size_t)(m0 + row) * CDIM;
    float vals[6];
    float s = 0.f;
#pragma unroll
    for (int i = 0; i < 6; i++) { vals[i] = xr[lane + i * 64]; s += vals[i]; }
#pragma unroll
    for (int o = 32; o > 0; o >>= 1) s += __shfl_xor(s, o);
    float mean = s * (1.f / 384.f);
    float vs = 0.f;
#pragma unroll
    for (int i = 0; i < 6; i++) { float d = vals[i] - mean; vs += d * d; }
#pragma unroll
    for (int o = 32; o > 0; o >>= 1) vs += __shfl_xor(vs, o);
    float rs = rsqrtf(vs * (1.f / 384.f) + 1e-5f);
#pragma unroll
    for (int i = 0; i < 6; i++) {
      int c = lane + i * 64;
      Al[row][c] = f2bf((vals[i] - mean) * rs * g[c] + b[c]);
    }
  }
  __syncthreads();

  for (int rd = 0; rd < 9; rd++) {
    int G = rd * 8 + wave;
    f32x4 acc[4] = {};
    const unsigned short* wb = WQF + (size_t)(G * 12) * 512 + lane * 8;
#pragma unroll
    for (int kk = 0; kk < 12; kk++) {
      short8 bf = *(const short8*)(wb + kk * 512);
#pragma unroll
      for (int i = 0; i < 4; i++) {
        short8 af = *(const short8*)&Al[i * 16 + l15][kk * 32 + l4 * 8];
        acc[i] = __builtin_amdgcn_mfma_f32_16x16x32_bf16(af, bf, acc[i], 0, 0, 0);
      }
    }
    int n = G * 16 + l15;
    float bv = BQ[n];
    __hip_bfloat16* dst = QKV + (size_t)m0 * QKVC + n;
#pragma unroll
    for (int i = 0; i < 4; i++)
#pragma unroll
      for (int r = 0; r < 4; r++)
        dst[(size_t)(i * 16 + l4 * 4 + r) * QKVC] = __float2bfloat16(acc[i][r] + bv);
  }
}

// ---------------- proj + residual: staged-A, one barrier, fragment-packed weights ----------------
__global__ __launch_bounds__(512) void proj_res(
    const __hip_bfloat16* __restrict__ AW, const unsigned short* __restrict__ WPF,
    const float* __restrict__ BP, const float* __restrict__ X,
    __hip_bfloat16* __restrict__ X1) {
  __shared__ unsigned short Al[64][388];
  int tid = threadIdx.x;
  int m0 = blockIdx.x * 64;
  int wave = tid >> 6, lane = tid & 63;
  int l15 = lane & 15, l4 = lane >> 4;

  {
#pragma unroll
    for (int i = 0; i < 6; i++) {
      int u = tid + i * 512;
      int r = u / 48, col = (u % 48) * 8;
      *(uint4*)&Al[r][col] =
          *(const uint4*)((const unsigned short*)AW + (size_t)(m0 + r) * 384 + col);
    }
  }
  __syncthreads();

  f32x4 acc[4][3] = {};
#pragma unroll
  for (int kk = 0; kk < 12; kk++) {
    short8 af[4];
#pragma unroll
    for (int i = 0; i < 4; i++)
      af[i] = *(const short8*)&Al[i * 16 + l15][kk * 32 + l4 * 8];
#pragma unroll
    for (int j = 0; j < 3; j++) {
      int G = wave * 3 + j;
      short8 bf = *(const short8*)(WPF + (size_t)(G * 12 + kk) * 512 + lane * 8);
#pragma unroll
      for (int i = 0; i < 4; i++)
        acc[i][j] = __builtin_amdgcn_mfma_f32_16x16x32_bf16(af[i], bf, acc[i][j], 0, 0, 0);
    }
  }
#pragma unroll
  for (int j = 0; j < 3; j++) {
    int n = (wave * 3 + j) * 16 + l15;
    float bv = BP[n];
#pragma unroll
    for (int i = 0; i < 4; i++)
#pragma unroll
      for (int r = 0; r < 4; r++) {
        int m = m0 + i * 16 + l4 * 4 + r;
        X1[(size_t)m * 384 + n] =
            __float2bfloat16(acc[i][j][r] + bv + X[(size_t)m * 384 + n]);
      }
  }
}

// -------- fused MLP (R19 best): 8 waves 1m x 8n, BM=64, W1-only register ping-pong --------
__global__ __launch_bounds__(512, 2) void mlp_fused(
    const __hip_bfloat16* __restrict__ XN, const unsigned short* __restrict__ W1F,
    const float* __restrict__ B1, const unsigned short* __restrict__ W2F,
    const float* __restrict__ B2, const __hip_bfloat16* __restrict__ X2,
    float* __restrict__ OUT) {
  __shared__ unsigned short XNl[64][388];
  __shared__ unsigned short Hl[64][132];
  int tid = threadIdx.x;
  int m0 = blockIdx.x * 64;
  int wave = tid >> 6, lane = tid & 63;
  int wn = wave;
  int l15 = lane & 15, l4 = lane >> 4;

  {
#pragma unroll
    for (int i = 0; i < 6; i++) {
      int u = tid + i * 512;
      int r = u / 48, col = (u % 48) * 8;
      *(uint4*)&XNl[r][col] =
          *(const uint4*)((const unsigned short*)XN + (size_t)(m0 + r) * 384 + col);
    }
  }

  f32x4 acc[4][3] = {};
  const unsigned short* w1b0 = W1F + (size_t)wn * 512 + lane * 8;
  short8 wA[12], wB[12];
#pragma unroll
  for (int kk = 0; kk < 12; kk++)
    wA[kk] = *(const short8*)(w1b0 + kk * 4096);

  __syncthreads();

  for (int S = 0; S < 6; S++) {
    {
      const int ks = 2 * S;
#pragma unroll
      for (int kk = 0; kk < 12; kk++)
        wB[kk] = *(const short8*)(w1b0 + (size_t)(ks + 1) * 49152 + kk * 4096);
      f32x4 hacc[4] = {};
#pragma unroll
      for (int kk = 0; kk < 12; kk++)
#pragma unroll
        for (int i = 0; i < 4; i++) {
          short8 af = *(const short8*)&XNl[i * 16 + l15][kk * 32 + l4 * 8];
          hacc[i] = __builtin_amdgcn_mfma_f32_16x16x32_bf16(af, wA[kk], hacc[i], 0, 0, 0);
        }
      float b1v = B1[ks * 128 + wn * 16 + l15];
      __syncthreads();
#pragma unroll
      for (int i = 0; i < 4; i++)
#pragma unroll
        for (int r = 0; r < 4; r++) {
          float c = hacc[i][r] + b1v;
          Hl[i * 16 + l4 * 4 + r][wn * 16 + l15] = f2bf(gelu_f(c));
        }
      __syncthreads();
      const unsigned short* w2fb = W2F + ((size_t)(ks * 96 + wn * 3)) * 512 + lane * 8;
#pragma unroll
      for (int kk = 0; kk < 4; kk++) {
        short8 af2[4];
#pragma unroll
        for (int i = 0; i < 4; i++)
          af2[i] = *(const short8*)&Hl[i * 16 + l15][kk * 32 + l4 * 8];
#pragma unroll
        for (int j = 0; j < 3; j++) {
          short8 bf2 = *(const short8*)(w2fb + kk * 12288 + j * 512);
#pragma unroll
          for (int i = 0; i < 4; i++)
            acc[i][j] = __builtin_amdgcn_mfma_f32_16x16x32_bf16(af2[i], bf2, acc[i][j], 0, 0, 0);
        }
      }
    }
    {
      const int ks = 2 * S + 1;
      const int ksn = (ks + 1 < 12) ? (ks + 1) : 0;
#pragma unroll
      for (int kk = 0; kk < 12; kk++)
        wA[kk] = *(const short8*)(w1b0 + (size_t)ksn * 49152 + kk * 4096);
      f32x4 hacc[4] = {};
#pragma unroll
      for (int kk = 0; kk < 12; kk++)
#pragma unroll
        for (int i = 0; i < 4; i++) {
          short8 af = *(const short8*)&XNl[i * 16 + l15][kk * 32 + l4 * 8];
          hacc[i] = __builtin_amdgcn_mfma_f32_16x16x32_bf16(af, wB[kk], hacc[i], 0, 0, 0);
        }
      float b1v = B1[ks * 128 + wn * 16 + l15];
      __syncthreads();
#pragma unroll
      for (int i = 0; i < 4; i++)
#pragma unroll
        for (int r = 0; r < 4; r++) {
          float c = hacc[i][r] + b1v;
          Hl[i * 16 + l4 * 4 + r][wn * 16 + l15] = f2bf(gelu_f(c));
        }
      __syncthreads();
      const unsigned short* w2fb = W2F + ((size_t)(ks * 96 + wn * 3)) * 512 + lane * 8;
#pragma unroll
      for (int kk = 0; kk < 4; kk++) {
        short8 af2[4];
#pragma unroll
        for (int i = 0; i < 4; i++)
          af2[i] = *(const short8*)&Hl[i * 16 + l15][kk * 32 + l4 * 8];
#pragma unroll
        for (int j = 0; j < 3; j++) {
          short8 bf2 = *(const short8*)(w2fb + kk * 12288 + j * 512);
#pragma unroll
          for (int i = 0; i < 4; i++)
            acc[i][j] = __builtin_amdgcn_mfma_f32_16x16x32_bf16(af2[i], bf2, acc[i][j], 0, 0, 0);
        }
      }
    }
  }
#pragma unroll
  for (int j = 0; j < 3; j++) {
    int n = wn * 48 + j * 16 + l15;
    float bv = B2[n];
#pragma unroll
    for (int i = 0; i < 4; i++)
#pragma unroll
      for (int r = 0; r < 4; r++) {
        int m = m0 + i * 16 + l4 * 4 + r;
        OUT[(size_t)m * 384 + n] =
            acc[i][j][r] + bv + __bfloat162float(X2[(size_t)m * 384 + n]);
      }
  }
}

// ---------------- MFMA window attention: 1 wave per (window, head) ----------------
__global__ __launch_bounds__(64) void attn_mfma(
    const __hip_bfloat16* __restrict__ qkv, const __hip_bfloat16* __restrict__ qkv_pad,
    const float* __restrict__ Bexp, __hip_bfloat16* __restrict__ aw) {
  int h = blockIdx.x % NHEAD;
  int w = blockIdx.x / NHEAD;
  int b = w / 25, wi = w % 25;
  int wh = wi / 5, wv = wi % 5;

  __shared__ unsigned short Q[64][40];
  __shared__ unsigned short K[64][40];
  __shared__ unsigned short Vt[32][72];
  __shared__ unsigned short P[64][72];

  int lane = threadIdx.x;
  int l15 = lane & 15, l4 = lane >> 4;

  {
    int t = lane;
    uint4 z = {0, 0, 0, 0};
    uint4 qv[4], kv[4];
    union { uint4 u[4]; unsigned short s[32]; } vu;
    bool use = t < 49;
    const unsigned short* src = (const unsigned short*)qkv_pad + h * 96;
    if (use) {
      int hh = wh * 7 + t / 7, ww = wv * 7 + t % 7;
      if (hh < 32 && ww < 32)
        src = (const unsigned short*)qkv + (size_t)(b * 1024 + hh * 32 + ww) * QKVC + h * 96;
    }
#pragma unroll
    for (int c = 0; c < 4; c++) {
      qv[c]   = use ? *(const uint4*)(src + c * 8)      : z;
      kv[c]   = use ? *(const uint4*)(src + 32 + c * 8) : z;
      vu.u[c] = use ? *(const uint4*)(src + 64 + c * 8) : z;
    }
#pragma unroll
    for (int c = 0; c < 4; c++) {
      *(uint4*)&Q[t][c * 8] = qv[c];
      *(uint4*)&K[t][c * 8] = kv[c];
    }
#pragma unroll
    for (int d = 0; d < 32; d++) Vt[d][t] = vu.s[d];
  }
  __syncthreads();

  f32x4 acc[4][4] = {};
  {
    short8 aq[4], bk[4];
#pragma unroll
    for (int i = 0; i < 4; i++) aq[i] = *(const short8*)&Q[i * 16 + l15][l4 * 8];
#pragma unroll
    for (int j = 0; j < 4; j++) bk[j] = *(const short8*)&K[j * 16 + l15][l4 * 8];
#pragma unroll
    for (int i = 0; i < 4; i++)
#pragma unroll
      for (int j = 0; j < 4; j++)
        acc[i][j] = __builtin_amdgcn_mfma_f32_16x16x32_bf16(aq[i], bk[j], acc[i][j], 0, 0, 0);
  }

  const float* Bh = Bexp + h * 4096;
  float rinv_[4][4];
#pragma unroll
  for (int i = 0; i < 4; i++) {
    float s[4][4];
#pragma unroll
    for (int j = 0; j < 4; j++)
#pragma unroll
      for (int r = 0; r < 4; r++) {
        int n = i * 16 + l4 * 4 + r, m = j * 16 + l15;
        s[j][r] = acc[i][j][r] * SCALE + Bh[n * 64 + m];
      }
#pragma unroll
    for (int r = 0; r < 4; r++) {
      float mx = fmaxf(fmaxf(s[0][r], s[1][r]), fmaxf(s[2][r], s[3][r]));
#pragma unroll
      for (int o = 1; o < 16; o <<= 1) mx = fmaxf(mx, __shfl_xor(mx, o));
      float p[4], sm = 0.f;
#pragma unroll
      for (int j = 0; j < 4; j++) { p[j] = __expf(s[j][r] - mx); sm += p[j]; }
#pragma unroll
      for (int o = 1; o < 16; o <<= 1) sm += __shfl_xor(sm, o);
      rinv_[i][r] = 1.f / sm;
      int n = i * 16 + l4 * 4 + r;
#pragma unroll
      for (int j = 0; j < 4; j++) P[n][j * 16 + l15] = f2bf(p[j]);
    }
  }
  __syncthreads();

  f32x4 o[4][2] = {};
#pragma unroll
  for (int ks = 0; ks < 2; ks++) {
    short8 pa[4], vb[2];
#pragma unroll
    for (int i = 0; i < 4; i++) pa[i] = *(const short8*)&P[i * 16 + l15][ks * 32 + l4 * 8];
#pragma unroll
    for (int j = 0; j < 2; j++) vb[j] = *(const short8*)&Vt[j * 16 + l15][ks * 32 + l4 * 8];
#pragma unroll
    for (int i = 0; i < 4; i++)
#pragma unroll
      for (int j = 0; j < 2; j++)
        o[i][j] = __builtin_amdgcn_mfma_f32_16x16x32_bf16(pa[i], vb[j], o[i][j], 0, 0, 0);
  }

#pragma unroll
  for (int i = 0; i < 4; i++)
#pragma unroll
    for (int r = 0; r < 4; r++) {
      int n = i * 16 + l4 * 4 + r;
      if (n < 49) {
        int hh = wh * 7 + n / 7, ww = wv * 7 + n % 7;
        if (hh < 32 && ww < 32) {
          __hip_bfloat16* dst = aw + (size_t)(b * 1024 + hh * 32 + ww) * CDIM + h * 32;
          float ri = rinv_[i][r];
#pragma unroll
          for (int j = 0; j < 2; j++)
            dst[j * 16 + l15] = __float2bfloat16(o[i][j][r] * ri);
        }
      }
    }
}

// ------- fused depthwise 3x3 conv + BN + LN2 (x1 bf16 in, x2 bf16 out) -------
__global__ __launch_bounds__(384) void conv_bn_ln_kernel(
    const __hip_bfloat16* __restrict__ X, const float* __restrict__ W9,
    const float* __restrict__ g, const float* __restrict__ bb,
    const float* __restrict__ mm, const float* __restrict__ vv,
    const float* __restrict__ lg, const float* __restrict__ lb,
    __hip_bfloat16* __restrict__ X2, __hip_bfloat16* __restrict__ XN) {
  int nwg = gridDim.x;
  int id = blockIdx.x;
  int nid = (id & 7) * (nwg >> 3) + (id >> 3);
  int yh = nid & 1;
  int x = (nid >> 1) & 31;
  int b = nid >> 6;
  int c = threadIdx.x;

  float w[9];
#pragma unroll
  for (int i = 0; i < 9; i++) w[i] = W9[c * 9 + i];
  float bnsc = rsqrtf(vv[c] + 1e-5f) * g[c];
  float bnsh = bb[c] - mm[c] * bnsc;
  float lgc = lg[c], lbc = lb[c];

  bool xm = x > 0, xp = x < 31;
  const __hip_bfloat16* colbase = X + ((size_t)(b * 1024 + x)) * CDIM + c;

  __shared__ float part[2][6][2];
  int wv = threadIdx.x >> 6, ln = threadIdx.x & 63;

  float w0[3], w1[3], w2[3];
  int y0 = yh * 16;
  if (y0 == 0) {
    w0[0] = w0[1] = w0[2] = 0.f;
  } else {
    const __hip_bfloat16* p = colbase + (size_t)(y0 - 1) * 32 * CDIM;
    w0[0] = xm ? __bfloat162float(p[-CDIM]) : 0.f;
    w0[1] = __bfloat162float(p[0]);
    w0[2] = xp ? __bfloat162float(p[CDIM]) : 0.f;
  }
  {
    const __hip_bfloat16* p = colbase + (size_t)y0 * 32 * CDIM;
    w1[0] = xm ? __bfloat162float(p[-CDIM]) : 0.f;
    w1[1] = __bfloat162float(p[0]);
    w1[2] = xp ? __bfloat162float(p[CDIM]) : 0.f;
  }

  for (int y = y0; y < y0 + 16; y++) {
    if (y + 1 < 32) {
      const __hip_bfloat16* p = colbase + (size_t)(y + 1) * 32 * CDIM;
      w2[0] = xm ? __bfloat162float(p[-CDIM]) : 0.f;
      w2[1] = __bfloat162float(p[0]);
      w2[2] = xp ? __bfloat162float(p[CDIM]) : 0.f;
    } else {
      w2[0] = w2[1] = w2[2] = 0.f;
    }
    float acc = w0[0] * w[0] + w0[1] * w[1] + w0[2] * w[2]
              + w1[0] * w[3] + w1[1] * w[4] + w1[2] * w[5]
              + w2[0] * w[6] + w2[1] * w[7] + w2[2] * w[8];
    float r = acc * bnsc + bnsh;
    size_t tok = (size_t)(b * 1024 + y * 32 + x);
    X2[tok * CDIM + c] = __float2bfloat16(r);

    float s1 = r, s2 = r * r;
#pragma unroll
    for (int o = 32; o > 0; o >>= 1) { s1 += __shfl_xor(s1, o); s2 += __shfl_xor(s2, o); }
    int pb = y & 1;
    if (ln == 0) { part[pb][wv][0] = s1; part[pb][wv][1] = s2; }
    __syncthreads();
    float ts1 = 0.f, ts2 = 0.f;
#pragma unroll
    for (int i = 0; i < 6; i++) { ts1 += part[pb][i][0]; ts2 += part[pb][i][1]; }
    float mean = ts1 * (1.f / 384.f);
    float var = ts2 * (1.f / 384.f) - mean * mean;
    float rstd = rsqrtf(var + 1e-5f);
    XN[tok * CDIM + c] = __float2bfloat16((r - mean) * rstd * lgc + lbc);

    w0[0] = w1[0]; w0[1] = w1[1]; w0[2] = w1[2];
    w1[0] = w2[0]; w1[1] = w2[1]; w1[2] = w2[2];
  }
}

extern "C" void kernel_launch(void* const* d_in, const int* in_sizes, int n_in,
                              void* d_out, int out_size, void* d_ws, size_t ws_size,
                              hipStream_t stream) {
  const float* x      = (const float*)d_in[0];
  const float* ln1_g  = (const float*)d_in[1];
  const float* ln1_b  = (const float*)d_in[2];
  const float* qkv_w  = (const float*)d_in[3];
  const float* qkv_b  = (const float*)d_in[4];
  const float* proj_w = (const float*)d_in[5];
  const float* proj_b = (const float*)d_in[6];
  const float* att_b  = (const float*)d_in[7];
  const float* conv_w = (const float*)d_in[8];
  const float* bn_g   = (const float*)d_in[9];
  const float* bn_b   = (const float*)d_in[10];
  const float* bn_m   = (const float*)d_in[11];
  const float* bn_v   = (const float*)d_in[12];
  const float* ln2_g  = (const float*)d_in[13];
  const float* ln2_b  = (const float*)d_in[14];
  const float* fc1_w  = (const float*)d_in[15];
  const float* fc1_b  = (const float*)d_in[16];
  const float* fc2_w  = (const float*)d_in[17];
  const float* fc2_b  = (const float*)d_in[18];
  const int* bias_idxs = (const int*)d_in[19];
  int n_off = in_sizes[7] / NHEAD;
  float* out = (float*)d_out;

  char* ws = (char*)d_ws;
  size_t off = 0;
  __hip_bfloat16* qkv_pad = (__hip_bfloat16*)(ws + off); off += QKVC * 2;
  off = (off + 255) & ~(size_t)255;
  float* Bexp = (float*)(ws + off); off += (size_t)NHEAD * 4096 * 4;
  unsigned short* wqf = (unsigned short*)(ws + off); off += (size_t)QKVC * CDIM * 2;
  unsigned short* wpf = (unsigned short*)(ws + off); off += (size_t)CDIM * CDIM * 2;
  unsigned short* w1f = (unsigned short*)(ws + off); off += (size_t)MLPH * CDIM * 2;
  unsigned short* w2f = (unsigned short*)(ws + off); off += (size_t)CDIM * MLPH * 2;
  size_t HDR = (off + 255) & ~(size_t)255;

  const size_t PER_TOK = 4608;
  int Bc = 64;
  while (Bc > 1 && HDR + (size_t)Bc * 1024 * PER_TOK > ws_size) Bc >>= 1;
  size_t Tc = (size_t)Bc * 1024;

  off = HDR;
  __hip_bfloat16* xn = (__hip_bfloat16*)(ws + off); off += Tc * CDIM * 2;
  __hip_bfloat16* qkv = (__hip_bfloat16*)(ws + off); off += Tc * QKVC * 2;
  __hip_bfloat16* x1 = qkv;  // alias: qkv dead after attn_mfma
  __hip_bfloat16* awb = (__hip_bfloat16*)(ws + off); off += Tc * CDIM * 2;
  __hip_bfloat16* x2 = (__hip_bfloat16*)(ws + off); off += Tc * CDIM * 2;

  pad_qkv_kernel<<<dim3(5), dim3(256), 0, stream>>>(ln1_b, qkv_w, qkv_b, qkv_pad);
  expand_bias<<<dim3(NHEAD), dim3(256), 0, stream>>>(att_b, bias_idxs, Bexp, n_off);
  wfragq<<<dim3(864), dim3(64), 0, stream>>>(qkv_w, wqf);
  wfragp<<<dim3(288), dim3(64), 0, stream>>>(proj_w, wpf);
  wfrag1<<<dim3(1152), dim3(64), 0, stream>>>(fc1_w, w1f);
  wfrag2<<<dim3(1152), dim3(64), 0, stream>>>(fc2_w, w2f);

  for (int b0 = 0; b0 < 64; b0 += Bc) {
    const float* xa = x + (size_t)b0 * 1024 * CDIM;
    float* outa = out + (size_t)b0 * 1024 * CDIM;
    int M = (int)Tc;

    ln_qkv<<<dim3(M / 64), dim3(512), 0, stream>>>(xa, ln1_g, ln1_b, wqf, qkv_b, qkv);
    attn_mfma<<<dim3(Bc * 25 * NHEAD), dim3(64), 0, stream>>>(qkv, qkv_pad, Bexp, awb);
    proj_res<<<dim3(M / 64), dim3(512), 0, stream>>>(awb, wpf, proj_b, xa, x1);
    conv_bn_ln_kernel<<<dim3(Bc * 64), dim3(384), 0, stream>>>(
        x1, conv_w, bn_g, bn_b, bn_m, bn_v, ln2_g, ln2_b, x2, xn);
    mlp_fused<<<dim3(M / 64), dim3(512), 0, stream>>>(
        xn, w1f, fc1_b, w2f, fc2_b, x2, outa);
  }
}